// Round 1
// baseline (204.328 us; speedup 1.0000x reference)
//
#include <hip/hip_runtime.h>
#include <hip/hip_bf16.h>

// GroupedVectorSA (gfx950) — ROUND 13: k_main restructured to 2 points/block
// (512 thr, 8 waves, 4 waves/point). LDS ~39.9KB -> 4 blocks/CU -> 32 waves/CU
// (was 75.4KB -> 2 blocks -> 16 waves). Per-point work/LDS traffic unchanged;
// relation K-split now 4-way. k_prep/k_qkv unchanged from R12.

typedef __attribute__((ext_vector_type(8))) short bf16x8_t;
typedef __attribute__((ext_vector_type(4))) float f32x4_t;

#define BN_EPS 1e-5f
#define WSYNC() asm volatile("s_waitcnt lgkmcnt(0)" ::: "memory")

__device__ __forceinline__ float blo(unsigned int v) {
    union { unsigned int u; float f; } x; x.u = v << 16; return x.f;
}
__device__ __forceinline__ float bhi(unsigned int v) {
    union { unsigned int u; float f; } x; x.u = v & 0xffff0000u; return x.f;
}
__device__ __forceinline__ unsigned int fbits(float f) {
    union { float f; unsigned int u; } x; x.f = f; return x.u;
}
__device__ __forceinline__ unsigned short f2b(float f) {      // RNE fp32->bf16
    unsigned int u = fbits(f);
    return (unsigned short)((u + 0x7fffu + ((u >> 16) & 1u)) >> 16);
}
__device__ __forceinline__ unsigned int f2bpk(float a, float b) {  // hw packed cvt
    union { __hip_bfloat162 h; unsigned int u; } x;
    x.h = __float22bfloat162_rn(make_float2(a, b));
    return x.u;
}
__device__ __forceinline__ unsigned int relpair(unsigned int kb, unsigned int qb,
                                                unsigned int pm_, unsigned int pb_) {
    float r0 = (blo(kb) - blo(qb)) * blo(pm_) + blo(pb_);
    float r1 = (bhi(kb) - bhi(qb)) * bhi(pm_) + bhi(pb_);
    return f2bpk(r0, r1);
}

// ---------------------------------------------------------------------------
// K0: blocks 0..159: 5 weights -> bf16 fragment-linear. 160: W4. 161: we1TF.
// ---------------------------------------------------------------------------
__global__ __launch_bounds__(256) void k_prep(
    const float* __restrict__ wq, const float* __restrict__ wk,
    const float* __restrict__ wv, const float* __restrict__ pm2,
    const float* __restrict__ pb2,
    const float* __restrict__ pm_w1, const float* __restrict__ pm_b1,
    const float* __restrict__ pm_bn,
    const float* __restrict__ pb_w1, const float* __restrict__ pb_b1,
    const float* __restrict__ pb_bn,
    const float* __restrict__ we_w1,
    unsigned short* __restrict__ wsT, float* __restrict__ W4,
    unsigned short* __restrict__ we1TF)
{
    const int bid = blockIdx.x, t = threadIdx.x;
    if (bid < 160) {
        __shared__ unsigned short T[32][72];
        const int mat = bid >> 5;
        const int kk  = (bid >> 2) & 7;
        const int ntq = bid & 3;
        const float* s = (mat == 0) ? wq : (mat == 1) ? wk : (mat == 2) ? wv
                         : (mat == 3) ? pm2 : pb2;
        {
            int c = t & 63, r0 = t >> 6;
            for (int i = 0; i < 8; ++i) {
                int r = r0 + i * 4;
                T[r][c] = f2b(s[(kk * 32 + r) * 256 + ntq * 64 + c]);
            }
        }
        __syncthreads();
        {
            int seg = t >> 6, lane = t & 63;
            int col = seg * 16 + (lane & 15);
            int kr  = (lane >> 4) * 8;
            unsigned int v[8];
            #pragma unroll
            for (int j = 0; j < 8; ++j) v[j] = T[kr + j][col];
            uint4 o;
            o.x = v[0] | (v[1] << 16);
            o.y = v[2] | (v[3] << 16);
            o.z = v[4] | (v[5] << 16);
            o.w = v[6] | (v[7] << 16);
            *(uint4*)(wsT + mat * 65536 + (ntq * 4 + seg) * 4096 + kk * 512 + lane * 8) = o;
        }
    } else if (bid == 160) {
        int c = t;
        float s = pm_bn[c] / sqrtf(pm_bn[768 + c] + BN_EPS);
        float4 wm = make_float4(pm_w1[c] * s, pm_w1[256 + c] * s, pm_w1[512 + c] * s,
                                (pm_b1[c] - pm_bn[512 + c]) * s + pm_bn[256 + c]);
        s = pb_bn[c] / sqrtf(pb_bn[768 + c] + BN_EPS);
        float4 wb = make_float4(pb_w1[c] * s, pb_w1[256 + c] * s, pb_w1[512 + c] * s,
                                (pb_b1[c] - pb_bn[512 + c]) * s + pb_bn[256 + c]);
        ((float4*)W4)[c]       = wm;
        ((float4*)W4)[256 + c] = wb;
    } else {
        for (int j = 0; j < 8; ++j) {
            int e = t * 8 + j;
            int g = e >> 8, c = e & 255;
            we1TF[g * 256 + c] = f2b(we_w1[c * 8 + g]);
        }
    }
}

// ---------------------------------------------------------------------------
// K1: q/k/v GEMM. grid=768, blk=256. (unchanged)
// ---------------------------------------------------------------------------
__global__ __launch_bounds__(256) void k_qkv(
    const float* __restrict__ feats,
    const unsigned short* __restrict__ wT,
    const float* __restrict__ bq, const float* __restrict__ bnq,
    const float* __restrict__ bk, const float* __restrict__ bnk,
    const float* __restrict__ bv,
    unsigned short* __restrict__ qkv)
{
    __shared__ unsigned short A[32][264];
    const int t    = threadIdx.x;
    const int widx = blockIdx.x >> 8;
    const int mb   = blockIdx.x & 255;

    for (int i = 0; i < 8; ++i) {
        int row = 4 * i + (t >> 6), col = (t & 63) * 4;
        float4 f = *(const float4*)(feats + (mb * 32 + row) * 256 + col);
        *(uint2*)&A[row][col] = make_uint2(f2bpk(f.x, f.y), f2bpk(f.z, f.w));
    }
    __syncthreads();

    const int lane = t & 63, w = t >> 6;
    const int ln15 = lane & 15, quad = lane >> 4;
    const int mt = w & 1, nh = w >> 1;

    bf16x8_t afr[8];
    #pragma unroll
    for (int kk = 0; kk < 8; ++kk)
        afr[kk] = *(const bf16x8_t*)&A[mt * 16 + ln15][kk * 32 + quad * 8];

    const unsigned short* W = wT + widx * 65536;
    const float* bias = (widx == 0) ? bq : (widx == 1) ? bk : bv;
    const float* bn   = (widx == 0) ? bnq : (widx == 1) ? bnk : nullptr;
    unsigned short* dst = qkv + (size_t)widx * 8192 * 256;

    f32x4_t acc[8];
    for (int j = 0; j < 8; ++j) acc[j] = (f32x4_t){0.f, 0.f, 0.f, 0.f};

    #pragma unroll
    for (int kk = 0; kk < 8; ++kk) {
        #pragma unroll
        for (int j = 0; j < 8; ++j) {
            int nt = nh * 8 + j;
            bf16x8_t bfr = *(const bf16x8_t*)(W + ((nt * 8 + kk) * 64 + lane) * 8);
            acc[j] = __builtin_amdgcn_mfma_f32_16x16x32_bf16(afr[kk], bfr, acc[j], 0, 0, 0);
        }
    }

    float bb[8], sc[8], mu[8], be[8];
    #pragma unroll
    for (int j = 0; j < 8; ++j) {
        int c = (nh * 8 + j) * 16 + ln15;
        bb[j] = bias[c];
        if (bn) {
            sc[j] = bn[c] / sqrtf(bn[768 + c] + BN_EPS);
            be[j] = bn[256 + c];
            mu[j] = bn[512 + c];
        }
    }
    __syncthreads();
    #pragma unroll
    for (int j = 0; j < 8; ++j) {
        int c = (nh * 8 + j) * 16 + ln15;
        float y[4];
        for (int r = 0; r < 4; ++r) {
            y[r] = acc[j][r] + bb[j];
            if (bn) y[r] = fmaxf((y[r] - mu[j]) * sc[j] + be[j], 0.f);
        }
        for (int r = 0; r < 4; r += 2) {
            unsigned int pk = f2bpk(y[r], y[r + 1]);
            A[mt * 16 + quad * 4 + r][c]     = (unsigned short)pk;
            A[mt * 16 + quad * 4 + r + 1][c] = (unsigned short)(pk >> 16);
        }
    }
    __syncthreads();
    {
        int row = t >> 3, cc = (t & 7) * 32;
        #pragma unroll
        for (int j = 0; j < 4; ++j) {
            uint4 v = *(const uint4*)&A[row][cc + 8 * j];
            *(uint4*)(dst + (mb * 32 + row) * 256 + cc + 8 * j) = v;
        }
    }
}

// ---------------------------------------------------------------------------
// K2: fused main. 512 threads (8 waves), 2 points/block, 4 waves per point.
// grid=4096. LDS ~39.9KB -> 4 blocks/CU -> 32 waves/CU.
// ---------------------------------------------------------------------------
__global__ __launch_bounds__(512, 8) void k_main(
    const float* __restrict__ coords,
    const int*   __restrict__ index,
    const unsigned short* __restrict__ qm,
    const unsigned short* __restrict__ km,
    const unsigned short* __restrict__ vm,
    const unsigned short* __restrict__ pmw2F,
    const unsigned short* __restrict__ pbw2F,
    const float* __restrict__ W4,
    const unsigned short* __restrict__ we1TF,
    const float* __restrict__ pm_b2, const float* __restrict__ pb_b2,
    const float* __restrict__ we_b1, const float* __restrict__ we_bn,
    const float* __restrict__ we_w2, const float* __restrict__ we_b2,
    float* __restrict__ out)
{
    __shared__ unsigned short bufR[32][264];   // h0 -> h1 -> pem
    __shared__ unsigned short bufP[32][264];   // peb
    __shared__ float posA[32][4];
    __shared__ float usP[4][32][8];            // partial logits (K-quarter)
    __shared__ float us_[32][8];               // logits -> softmax w
    __shared__ int   rowg_[32];
    __shared__ float we2s[8][8];
    __shared__ float web2[8], swe8[8], dwe8[8];

    const int t   = threadIdx.x;
    const int P0  = blockIdx.x * 2;
    const int bb_ = P0 >> 12;
    const int w = t >> 6, lane = t & 63;
    const int ln15 = lane & 15, quad = lane >> 4;
    const int p   = w >> 2, sub = w & 3;       // 4 waves own point p, K-quarter sub
    const int R0  = p * 16;
    const int Pg  = P0 + p;

    // ---- per-lane neighbor row (s=ln15) + k prefetch, K-quarter = sub ----
    const int rg = (bb_ << 12) + index[Pg * 16 + ln15];
    uint4 kpre[2];
    #pragma unroll
    for (int kk = 0; kk < 2; ++kk)
        kpre[kk] = *(const uint4*)(km + rg * 256 + (sub * 2 + kk) * 32 + quad * 8);

    // ---- per-wave pos/rowg staging: own 4 rows (lanes<4) ----
    if (lane < 4) {
        int m  = w * 4 + lane;
        int Pr = P0 + (m >> 4);
        int rs = (bb_ << 12) + index[Pr * 16 + (m & 15)];
        rowg_[m]   = rs;
        posA[m][0] = coords[Pr * 3 + 0] - coords[rs * 3 + 0];
        posA[m][1] = coords[Pr * 3 + 1] - coords[rs * 3 + 1];
        posA[m][2] = coords[Pr * 3 + 2] - coords[rs * 3 + 2];
        posA[m][3] = 0.f;
    }
    if (t < 64) we2s[t >> 3][t & 7] = we_w2[t];
    if (t < 8) {
        float s = we_bn[t] / sqrtf(we_bn[24 + t] + BN_EPS);
        swe8[t] = s;
        dwe8[t] = (we_b1[t] - we_bn[16 + t]) * s + we_bn[8 + t];
        web2[t] = we_b2[t];
    }
    WSYNC();

    const int hc = lane * 4;                   // h-build: 4 cols per lane
    const int hm = w * 4;                      // and 4 rows per wave

    // ---- h0 (pb hidden) -> bufR (own rows -> wave-local) ----
    {
        float4 c0 = ((const float4*)W4)[256 + hc];
        float4 c1 = ((const float4*)W4)[256 + hc + 1];
        float4 c2 = ((const float4*)W4)[256 + hc + 2];
        float4 c3 = ((const float4*)W4)[256 + hc + 3];
        #pragma unroll
        for (int m = 0; m < 4; ++m) {
            float4 pp = *(const float4*)&posA[hm + m][0];
            float h0 = fmaxf(pp.x * c0.x + pp.y * c0.y + pp.z * c0.z + c0.w, 0.f);
            float h1 = fmaxf(pp.x * c1.x + pp.y * c1.y + pp.z * c1.z + c1.w, 0.f);
            float h2 = fmaxf(pp.x * c2.x + pp.y * c2.y + pp.z * c2.z + c2.w, 0.f);
            float h3 = fmaxf(pp.x * c3.x + pp.y * c3.y + pp.z * c3.z + c3.w, 0.f);
            *(uint2*)&bufR[hm + m][hc] = make_uint2(f2bpk(h0, h1), f2bpk(h2, h3));
        }
    }
    __syncthreads();                           // B1

    // ---- pass0 MFMA: peb. wave = 2 mt x 2 nt tiles, acc init = bias ----
    f32x4_t acc[2][2];
    {
        float b0 = pb_b2[(w * 2    ) * 16 + ln15];
        float b1 = pb_b2[(w * 2 + 1) * 16 + ln15];
        for (int mt = 0; mt < 2; ++mt) {
            acc[0][mt] = (f32x4_t){b0, b0, b0, b0};
            acc[1][mt] = (f32x4_t){b1, b1, b1, b1};
        }
    }
    #pragma unroll
    for (int kk = 0; kk < 8; ++kk) {
        bf16x8_t afr[2];
        #pragma unroll
        for (int mt = 0; mt < 2; ++mt)
            afr[mt] = *(const bf16x8_t*)&bufR[mt * 16 + ln15][kk * 32 + quad * 8];
        #pragma unroll
        for (int ntl = 0; ntl < 2; ++ntl) {
            int nt = w * 2 + ntl;
            bf16x8_t bfr = *(const bf16x8_t*)(pbw2F + ((nt * 8 + kk) * 64 + lane) * 8);
            #pragma unroll
            for (int mt = 0; mt < 2; ++mt)
                acc[ntl][mt] = __builtin_amdgcn_mfma_f32_16x16x32_bf16(afr[mt], bfr, acc[ntl][mt], 0, 0, 0);
        }
    }
    __syncthreads();                           // B2 (h0 reads done)

    // peb epilogue -> bufP
    #pragma unroll
    for (int ntl = 0; ntl < 2; ++ntl) {
        int c = (w * 2 + ntl) * 16 + ln15;
        for (int mt = 0; mt < 2; ++mt)
            for (int r = 0; r < 4; r += 2) {
                unsigned int pk = f2bpk(acc[ntl][mt][r], acc[ntl][mt][r + 1]);
                bufP[mt * 16 + quad * 4 + r][c]     = (unsigned short)pk;
                bufP[mt * 16 + quad * 4 + r + 1][c] = (unsigned short)(pk >> 16);
            }
    }
    // h1 (pm hidden) -> bufR
    {
        float4 c0 = ((const float4*)W4)[hc];
        float4 c1 = ((const float4*)W4)[hc + 1];
        float4 c2 = ((const float4*)W4)[hc + 2];
        float4 c3 = ((const float4*)W4)[hc + 3];
        #pragma unroll
        for (int m = 0; m < 4; ++m) {
            float4 pp = *(const float4*)&posA[hm + m][0];
            float h0 = fmaxf(pp.x * c0.x + pp.y * c0.y + pp.z * c0.z + c0.w, 0.f);
            float h1 = fmaxf(pp.x * c1.x + pp.y * c1.y + pp.z * c1.z + c1.w, 0.f);
            float h2 = fmaxf(pp.x * c2.x + pp.y * c2.y + pp.z * c2.z + c2.w, 0.f);
            float h3 = fmaxf(pp.x * c3.x + pp.y * c3.y + pp.z * c3.z + c3.w, 0.f);
            *(uint2*)&bufR[hm + m][hc] = make_uint2(f2bpk(h0, h1), f2bpk(h2, h3));
        }
    }
    __syncthreads();                           // B3

    // ---- pass1 MFMA: pem, acc init = bias ----
    {
        float b0 = pm_b2[(w * 2    ) * 16 + ln15];
        float b1 = pm_b2[(w * 2 + 1) * 16 + ln15];
        for (int mt = 0; mt < 2; ++mt) {
            acc[0][mt] = (f32x4_t){b0, b0, b0, b0};
            acc[1][mt] = (f32x4_t){b1, b1, b1, b1};
        }
    }
    #pragma unroll
    for (int kk = 0; kk < 8; ++kk) {
        bf16x8_t afr[2];
        #pragma unroll
        for (int mt = 0; mt < 2; ++mt)
            afr[mt] = *(const bf16x8_t*)&bufR[mt * 16 + ln15][kk * 32 + quad * 8];
        #pragma unroll
        for (int ntl = 0; ntl < 2; ++ntl) {
            int nt = w * 2 + ntl;
            bf16x8_t bfr = *(const bf16x8_t*)(pmw2F + ((nt * 8 + kk) * 64 + lane) * 8);
            #pragma unroll
            for (int mt = 0; mt < 2; ++mt)
                acc[ntl][mt] = __builtin_amdgcn_mfma_f32_16x16x32_bf16(afr[mt], bfr, acc[ntl][mt], 0, 0, 0);
        }
    }
    __syncthreads();                           // B4 (h1 reads done)

    // pem epilogue -> bufR
    #pragma unroll
    for (int ntl = 0; ntl < 2; ++ntl) {
        int c = (w * 2 + ntl) * 16 + ln15;
        for (int mt = 0; mt < 2; ++mt)
            for (int r = 0; r < 4; r += 2) {
                unsigned int pk = f2bpk(acc[ntl][mt][r], acc[ntl][mt][r + 1]);
                bufR[mt * 16 + quad * 4 + r][c]     = (unsigned short)pk;
                bufR[mt * 16 + quad * 4 + r + 1][c] = (unsigned short)(pk >> 16);
            }
    }
    __syncthreads();                           // B5 (pem/peb visible)

    // ---- relation + partial logits (K-quarter = sub), in registers ----
    {
        const bf16x8_t bz = {0, 0, 0, 0, 0, 0, 0, 0};
        f32x4_t lacc = {0.f, 0.f, 0.f, 0.f};
        #pragma unroll
        for (int kk = 0; kk < 2; ++kk) {
            int cb8 = (sub * 2 + kk) * 32 + quad * 8;
            uint4 pm4 = *(const uint4*)&bufR[R0 + ln15][cb8];
            uint4 pb4 = *(const uint4*)&bufP[R0 + ln15][cb8];
            uint4 q4  = *(const uint4*)(qm + Pg * 256 + cb8);
            union { uint4 u; bf16x8_t v; } rr;
            rr.u.x = relpair(kpre[kk].x, q4.x, pm4.x, pb4.x);
            rr.u.y = relpair(kpre[kk].y, q4.y, pm4.y, pb4.y);
            rr.u.z = relpair(kpre[kk].z, q4.z, pm4.z, pb4.z);
            rr.u.w = relpair(kpre[kk].w, q4.w, pm4.w, pb4.w);
            bf16x8_t bfr = bz;
            if (ln15 < 8) bfr = *(const bf16x8_t*)(we1TF + ln15 * 256 + cb8);
            lacc = __builtin_amdgcn_mfma_f32_16x16x32_bf16(rr.v, bfr, lacc, 0, 0, 0);
        }
        if (ln15 < 8) {
            #pragma unroll
            for (int r = 0; r < 4; ++r)
                usP[sub][R0 + quad * 4 + r][ln15] = lacc[r];
        }
    }
    __syncthreads();                           // B6 (partials visible)

    // ---- combine + BN/relu + logits2 (sub==0 wave, lanes<16 = s) ----
    if (sub == 0 && lane < 16) {
        int s = lane;
        float uv[8], l[8];
        #pragma unroll
        for (int g = 0; g < 8; ++g) {
            float x = usP[0][R0 + s][g] + usP[1][R0 + s][g]
                    + usP[2][R0 + s][g] + usP[3][R0 + s][g];
            uv[g] = fmaxf(x * swe8[g] + dwe8[g], 0.f);
        }
        #pragma unroll
        for (int g = 0; g < 8; ++g) {
            float x = web2[g];
            for (int gp = 0; gp < 8; ++gp) x += uv[gp] * we2s[gp][g];
            l[g] = x;
        }
        #pragma unroll
        for (int g = 0; g < 8; ++g) us_[R0 + s][g] = l[g];
    }
    WSYNC();

    // ---- softmax over s (sub==0 wave, lanes<8 = g) ----
    if (sub == 0 && lane < 8) {
        int g = lane;
        float mx = -1e30f;
        for (int s = 0; s < 16; ++s) mx = fmaxf(mx, us_[R0 + s][g]);
        float e[16], sum = 0.f;
        for (int s = 0; s < 16; ++s) { e[s] = __expf(us_[R0 + s][g] - mx); sum += e[s]; }
        float inv = 1.f / sum;
        for (int s = 0; s < 16; ++s) us_[R0 + s][g] = e[s] * inv;
    }
    __syncthreads();                           // B7 (softmax visible)

    // ---- output: 4 waves = 256 lanes per point, 1 col each ----
    {
        int c = sub * 64 + lane;
        int g = c >> 5;
        float a0 = 0.f;
        #pragma unroll
        for (int s = 0; s < 16; ++s) {
            int rv = rowg_[R0 + s];
            float wv_ = us_[R0 + s][g];
            unsigned int v2 = vm[rv * 256 + c];
            unsigned int p2 = bufP[R0 + s][c];
            a0 += wv_ * (blo(v2) + blo(p2));
        }
        out[(size_t)Pg * 256 + c] = a0;
    }
}

// ---------------------------------------------------------------------------
extern "C" void kernel_launch(void* const* d_in, const int* in_sizes, int n_in,
                              void* d_out, int out_size, void* d_ws, size_t ws_size,
                              hipStream_t stream)
{
    const float* feats  = (const float*)d_in[0];
    const float* coords = (const float*)d_in[1];
    const int*   index  = (const int*)d_in[2];
    const float* wq     = (const float*)d_in[3];
    const float* bq     = (const float*)d_in[4];
    const float* bnq    = (const float*)d_in[5];
    const float* wk     = (const float*)d_in[6];
    const float* bk     = (const float*)d_in[7];
    const float* bnk    = (const float*)d_in[8];
    const float* wv     = (const float*)d_in[9];
    const float* bv     = (const float*)d_in[10];
    const float* pm_w1  = (const float*)d_in[11];
    const float* pm_b1  = (const float*)d_in[12];
    const float* pm_bn  = (const float*)d_in[13];
    const float* pm_w2  = (const float*)d_in[14];
    const float* pm_b2  = (const float*)d_in[15];
    const float* pb_w1  = (const float*)d_in[16];
    const float* pb_b1  = (const float*)d_in[17];
    const float* pb_bn  = (const float*)d_in[18];
    const float* pb_w2  = (const float*)d_in[19];
    const float* pb_b2  = (const float*)d_in[20];
    const float* we_w1  = (const float*)d_in[21];
    const float* we_b1  = (const float*)d_in[22];
    const float* we_bn  = (const float*)d_in[23];
    const float* we_w2  = (const float*)d_in[24];
    const float* we_b2  = (const float*)d_in[25];

    unsigned short* qkv   = (unsigned short*)d_ws;
    unsigned short* wsT   = qkv + (size_t)3 * 8192 * 256;
    float*          W4    = (float*)(wsT + 5 * 65536);
    unsigned short* we1TF = (unsigned short*)(W4 + 2048);

    const size_t need = (size_t)13238272 + 8192 + 4096;
    if (ws_size < need) {
        hipMemsetAsync(d_out, 0, (size_t)out_size * 4, stream);
        return;
    }

    k_prep<<<162,  256, 0, stream>>>(wq, wk, wv, pm_w2, pb_w2,
                                     pm_w1, pm_b1, pm_bn,
                                     pb_w1, pb_b1, pb_bn,
                                     we_w1, wsT, W4, we1TF);
    k_qkv <<<768,  256, 0, stream>>>(feats, wsT, bq, bnq, bk, bnk, bv, qkv);
    k_main<<<4096, 512, 0, stream>>>(coords, index,
                                     qkv,
                                     qkv + (size_t)8192 * 256,
                                     qkv + (size_t)2 * 8192 * 256,
                                     wsT + 3 * 65536,
                                     wsT + 4 * 65536,
                                     W4, we1TF,
                                     pm_b2, pb_b2,
                                     we_b1, we_bn, we_w2, we_b2,
                                     (float*)d_out);
}

// Round 2
// 198.115 us; speedup vs baseline: 1.0314x; 1.0314x over previous
//
#include <hip/hip_runtime.h>
#include <hip/hip_bf16.h>

// GroupedVectorSA (gfx950) — ROUND 14: revert to R12 skeleton (4 pts/block,
// 512 thr, 2 waves/point, grid 2048). NEW: h-builds (pos@W1 for pm/pb) moved
// from VALU to MFMA via hi/lo bf16 K-slot packing (fp32-accurate). W1 packed
// into B-fragment layout by k_prep. q-tile prefetched during pem phase.

typedef __attribute__((ext_vector_type(8))) short bf16x8_t;
typedef __attribute__((ext_vector_type(4))) float f32x4_t;

#define BN_EPS 1e-5f
#define WSYNC() asm volatile("s_waitcnt lgkmcnt(0)" ::: "memory")

__device__ __forceinline__ float blo(unsigned int v) {
    union { unsigned int u; float f; } x; x.u = v << 16; return x.f;
}
__device__ __forceinline__ float bhi(unsigned int v) {
    union { unsigned int u; float f; } x; x.u = v & 0xffff0000u; return x.f;
}
__device__ __forceinline__ unsigned int fbits(float f) {
    union { float f; unsigned int u; } x; x.f = f; return x.u;
}
__device__ __forceinline__ unsigned short f2b(float f) {      // RNE fp32->bf16
    unsigned int u = fbits(f);
    return (unsigned short)((u + 0x7fffu + ((u >> 16) & 1u)) >> 16);
}
__device__ __forceinline__ float b2f(unsigned short h) {      // bf16->fp32 exact
    union { unsigned int u; float f; } x; x.u = ((unsigned int)h) << 16; return x.f;
}
__device__ __forceinline__ unsigned int f2bpk(float a, float b) {  // hw packed cvt
    union { __hip_bfloat162 h; unsigned int u; } x;
    x.h = __float22bfloat162_rn(make_float2(a, b));
    return x.u;
}
__device__ __forceinline__ unsigned int relpair(unsigned int kb, unsigned int qb,
                                                unsigned int pm_, unsigned int pb_) {
    float r0 = (blo(kb) - blo(qb)) * blo(pm_) + blo(pb_);
    float r1 = (bhi(kb) - bhi(qb)) * bhi(pm_) + bhi(pb_);
    return f2bpk(r0, r1);
}

// ---------------------------------------------------------------------------
// K0: blocks 0..159: 5 weights -> bf16 fragment-linear. 160: W1 frags. 161: we1TF.
// ---------------------------------------------------------------------------
__global__ __launch_bounds__(256) void k_prep(
    const float* __restrict__ wq, const float* __restrict__ wk,
    const float* __restrict__ wv, const float* __restrict__ pm2,
    const float* __restrict__ pb2,
    const float* __restrict__ pm_w1, const float* __restrict__ pm_b1,
    const float* __restrict__ pm_bn,
    const float* __restrict__ pb_w1, const float* __restrict__ pb_b1,
    const float* __restrict__ pb_bn,
    const float* __restrict__ we_w1,
    unsigned short* __restrict__ wsT, unsigned short* __restrict__ w1F,
    unsigned short* __restrict__ we1TF)
{
    const int bid = blockIdx.x, t = threadIdx.x;
    if (bid < 160) {
        __shared__ unsigned short T[32][72];
        const int mat = bid >> 5;
        const int kk  = (bid >> 2) & 7;
        const int ntq = bid & 3;
        const float* s = (mat == 0) ? wq : (mat == 1) ? wk : (mat == 2) ? wv
                         : (mat == 3) ? pm2 : pb2;
        {
            int c = t & 63, r0 = t >> 6;
            for (int i = 0; i < 8; ++i) {
                int r = r0 + i * 4;
                T[r][c] = f2b(s[(kk * 32 + r) * 256 + ntq * 64 + c]);
            }
        }
        __syncthreads();
        {
            int seg = t >> 6, lane = t & 63;
            int col = seg * 16 + (lane & 15);
            int kr  = (lane >> 4) * 8;
            unsigned int v[8];
            #pragma unroll
            for (int j = 0; j < 8; ++j) v[j] = T[kr + j][col];
            uint4 o;
            o.x = v[0] | (v[1] << 16);
            o.y = v[2] | (v[3] << 16);
            o.z = v[4] | (v[5] << 16);
            o.w = v[6] | (v[7] << 16);
            *(uint4*)(wsT + mat * 65536 + (ntq * 4 + seg) * 4096 + kk * 512 + lane * 8) = o;
        }
    } else if (bid == 160) {
        // Build W1 B-fragments (K-slot packed, BN folded), pass0=pm, pass1=pb.
        int c = t;                      // column 0..255
        int nt = c >> 4, l15 = c & 15;
        float sm = pm_bn[c] / sqrtf(pm_bn[768 + c] + BN_EPS);
        float sb = pb_bn[c] / sqrtf(pb_bn[768 + c] + BN_EPS);
        float W[2][4];
        W[0][0] = pm_w1[c] * sm; W[0][1] = pm_w1[256 + c] * sm;
        W[0][2] = pm_w1[512 + c] * sm;
        W[0][3] = (pm_b1[c] - pm_bn[512 + c]) * sm + pm_bn[256 + c];
        W[1][0] = pb_w1[c] * sb; W[1][1] = pb_w1[256 + c] * sb;
        W[1][2] = pb_w1[512 + c] * sb;
        W[1][3] = (pb_b1[c] - pb_bn[512 + c]) * sb + pb_bn[256 + c];
        for (int pass = 0; pass < 2; ++pass) {
            unsigned short xh = f2b(W[pass][0]), xl = f2b(W[pass][0] - b2f(xh));
            unsigned short yh = f2b(W[pass][1]), yl = f2b(W[pass][1] - b2f(yh));
            unsigned short zh = f2b(W[pass][2]), zl = f2b(W[pass][2] - b2f(zh));
            unsigned short bh = f2b(W[pass][3]), bl = f2b(W[pass][3] - b2f(bh));
            unsigned short sl[16] = { xh, xh, xl, yh, yh, yl, zh, zh, zl,
                                      bh, bl, 0, 0, 0, 0, 0 };
            for (int q = 0; q < 4; ++q)
                for (int j = 0; j < 8; ++j)
                    w1F[((pass * 16 + nt) * 64 + q * 16 + l15) * 8 + j] =
                        (q < 2) ? sl[q * 8 + j] : (unsigned short)0;
        }
    } else {
        for (int j = 0; j < 8; ++j) {
            int e = t * 8 + j;
            int g = e >> 8, c = e & 255;
            we1TF[g * 256 + c] = f2b(we_w1[c * 8 + g]);
        }
    }
}

// ---------------------------------------------------------------------------
// K1: q/k/v GEMM. grid=768, blk=256. (unchanged)
// ---------------------------------------------------------------------------
__global__ __launch_bounds__(256) void k_qkv(
    const float* __restrict__ feats,
    const unsigned short* __restrict__ wT,
    const float* __restrict__ bq, const float* __restrict__ bnq,
    const float* __restrict__ bk, const float* __restrict__ bnk,
    const float* __restrict__ bv,
    unsigned short* __restrict__ qkv)
{
    __shared__ unsigned short A[32][264];
    const int t    = threadIdx.x;
    const int widx = blockIdx.x >> 8;
    const int mb   = blockIdx.x & 255;

    for (int i = 0; i < 8; ++i) {
        int row = 4 * i + (t >> 6), col = (t & 63) * 4;
        float4 f = *(const float4*)(feats + (mb * 32 + row) * 256 + col);
        *(uint2*)&A[row][col] = make_uint2(f2bpk(f.x, f.y), f2bpk(f.z, f.w));
    }
    __syncthreads();

    const int lane = t & 63, w = t >> 6;
    const int ln15 = lane & 15, quad = lane >> 4;
    const int mt = w & 1, nh = w >> 1;

    bf16x8_t afr[8];
    #pragma unroll
    for (int kk = 0; kk < 8; ++kk)
        afr[kk] = *(const bf16x8_t*)&A[mt * 16 + ln15][kk * 32 + quad * 8];

    const unsigned short* W = wT + widx * 65536;
    const float* bias = (widx == 0) ? bq : (widx == 1) ? bk : bv;
    const float* bn   = (widx == 0) ? bnq : (widx == 1) ? bnk : nullptr;
    unsigned short* dst = qkv + (size_t)widx * 8192 * 256;

    f32x4_t acc[8];
    for (int j = 0; j < 8; ++j) acc[j] = (f32x4_t){0.f, 0.f, 0.f, 0.f};

    #pragma unroll
    for (int kk = 0; kk < 8; ++kk) {
        #pragma unroll
        for (int j = 0; j < 8; ++j) {
            int nt = nh * 8 + j;
            bf16x8_t bfr = *(const bf16x8_t*)(W + ((nt * 8 + kk) * 64 + lane) * 8);
            acc[j] = __builtin_amdgcn_mfma_f32_16x16x32_bf16(afr[kk], bfr, acc[j], 0, 0, 0);
        }
    }

    float bb[8], sc[8], mu[8], be[8];
    #pragma unroll
    for (int j = 0; j < 8; ++j) {
        int c = (nh * 8 + j) * 16 + ln15;
        bb[j] = bias[c];
        if (bn) {
            sc[j] = bn[c] / sqrtf(bn[768 + c] + BN_EPS);
            be[j] = bn[256 + c];
            mu[j] = bn[512 + c];
        }
    }
    __syncthreads();
    #pragma unroll
    for (int j = 0; j < 8; ++j) {
        int c = (nh * 8 + j) * 16 + ln15;
        float y[4];
        for (int r = 0; r < 4; ++r) {
            y[r] = acc[j][r] + bb[j];
            if (bn) y[r] = fmaxf((y[r] - mu[j]) * sc[j] + be[j], 0.f);
        }
        for (int r = 0; r < 4; r += 2) {
            unsigned int pk = f2bpk(y[r], y[r + 1]);
            A[mt * 16 + quad * 4 + r][c]     = (unsigned short)pk;
            A[mt * 16 + quad * 4 + r + 1][c] = (unsigned short)(pk >> 16);
        }
    }
    __syncthreads();
    {
        int row = t >> 3, cc = (t & 7) * 32;
        #pragma unroll
        for (int j = 0; j < 4; ++j) {
            uint4 v = *(const uint4*)&A[row][cc + 8 * j];
            *(uint4*)(dst + (mb * 32 + row) * 256 + cc + 8 * j) = v;
        }
    }
}

// ---------------------------------------------------------------------------
// K2: fused main. 512 threads (8 waves), 4 points/block, wave pair per point.
// grid=2048. LDS ~78.4KB -> 2 blocks/CU. h-builds via MFMA (K-slot hi/lo).
// ---------------------------------------------------------------------------
__global__ __launch_bounds__(512, 4) void k_main(
    const float* __restrict__ coords,
    const int*   __restrict__ index,
    const unsigned short* __restrict__ qm,
    const unsigned short* __restrict__ km,
    const unsigned short* __restrict__ vm,
    const unsigned short* __restrict__ pmw2F,
    const unsigned short* __restrict__ pbw2F,
    const unsigned short* __restrict__ w1F,
    const unsigned short* __restrict__ we1TF,
    const float* __restrict__ pm_b2, const float* __restrict__ pb_b2,
    const float* __restrict__ we_b1, const float* __restrict__ we_bn,
    const float* __restrict__ we_w2, const float* __restrict__ we_b2,
    float* __restrict__ out)
{
    __shared__ unsigned short bufR[64][264];   // h_pb -> h_pm -> pem
    __shared__ unsigned short bufP[64][264];   // peb
    __shared__ unsigned short posX[64][32];    // A-operand K-slots (hi/lo packed)
    __shared__ float usP[2][64][8];            // partial logits (K-split halves)
    __shared__ float us_[64][8];               // logits -> softmax w
    __shared__ int   rowg_[64];
    __shared__ float we2s[8][8];
    __shared__ float web2[8], swe8[8], dwe8[8];

    const int t   = threadIdx.x;
    const int P0  = blockIdx.x * 4;
    const int bb_ = P0 >> 12;
    const int w = t >> 6, lane = t & 63;
    const int ln15 = lane & 15, quad = lane >> 4;
    const int p   = w >> 1, sub = w & 1;       // wave pair (2p, 2p+1) owns point p
    const int R0  = p * 16;
    const int Pg  = P0 + p;

    // ---- per-lane neighbor row (s=ln15) + k prefetch, K-half sub ----
    const int rg = (bb_ << 12) + index[Pg * 16 + ln15];
    uint4 kpre[4];
    #pragma unroll
    for (int kk = 0; kk < 4; ++kk)
        kpre[kk] = *(const uint4*)(km + rg * 256 + (sub * 4 + kk) * 32 + quad * 8);

    // ---- stage posX K-slots (t<64 -> row m=t) + small consts ----
    if (t < 64) {
        int m  = t;
        int Pr = P0 + (m >> 4);
        int rs = (bb_ << 12) + index[Pr * 16 + (m & 15)];
        rowg_[m] = rs;
        float x = coords[Pr * 3 + 0] - coords[rs * 3 + 0];
        float y = coords[Pr * 3 + 1] - coords[rs * 3 + 1];
        float z = coords[Pr * 3 + 2] - coords[rs * 3 + 2];
        unsigned short xh = f2b(x), xl = f2b(x - b2f(xh));
        unsigned short yh = f2b(y), yl = f2b(y - b2f(yh));
        unsigned short zh = f2b(z), zl = f2b(z - b2f(zh));
        const unsigned short one = 0x3f80;
        posX[m][0] = xh; posX[m][1] = xl; posX[m][2] = xh;
        posX[m][3] = yh; posX[m][4] = yl; posX[m][5] = yh;
        posX[m][6] = zh; posX[m][7] = zl; posX[m][8] = zh;
        posX[m][9] = one; posX[m][10] = one;
        #pragma unroll
        for (int j2 = 11; j2 < 32; ++j2) posX[m][j2] = 0;
        we2s[m >> 3][m & 7] = we_w2[m];
    }
    if (t < 8) {
        float s = we_bn[t] / sqrtf(we_bn[24 + t] + BN_EPS);
        swe8[t] = s;
        dwe8[t] = (we_b1[t] - we_bn[16 + t]) * s + we_bn[8 + t];
        web2[t] = we_b2[t];
    }
    __syncthreads();                           // B1 (posX visible)

    // ---- A-fragments for pos (shared by both h-MFMAs, held in regs) ----
    bf16x8_t afrP[4];
    #pragma unroll
    for (int mt = 0; mt < 4; ++mt)
        afrP[mt] = *(const bf16x8_t*)&posX[mt * 16 + ln15][quad * 8];

    // ---- h_pb = relu(pos @ W1pb) via MFMA -> bufR ----
    {
        f32x4_t hb[2][4];
        for (int ntl = 0; ntl < 2; ++ntl)
            for (int mt = 0; mt < 4; ++mt) hb[ntl][mt] = (f32x4_t){0.f, 0.f, 0.f, 0.f};
        #pragma unroll
        for (int ntl = 0; ntl < 2; ++ntl) {
            int nt = w * 2 + ntl;
            bf16x8_t bfr = *(const bf16x8_t*)(w1F + ((16 + nt) * 64 + lane) * 8);
            #pragma unroll
            for (int mt = 0; mt < 4; ++mt)
                hb[ntl][mt] = __builtin_amdgcn_mfma_f32_16x16x32_bf16(afrP[mt], bfr, hb[ntl][mt], 0, 0, 0);
        }
        #pragma unroll
        for (int ntl = 0; ntl < 2; ++ntl) {
            int c = (w * 2 + ntl) * 16 + ln15;
            for (int mt = 0; mt < 4; ++mt)
                for (int r = 0; r < 4; r += 2) {
                    unsigned int pk = f2bpk(fmaxf(hb[ntl][mt][r], 0.f),
                                            fmaxf(hb[ntl][mt][r + 1], 0.f));
                    bufR[mt * 16 + quad * 4 + r][c]     = (unsigned short)pk;
                    bufR[mt * 16 + quad * 4 + r + 1][c] = (unsigned short)(pk >> 16);
                }
        }
    }
    __syncthreads();                           // B2 (h_pb visible)

    // ---- phase: peb MFMA (bufR @ w2pb) + h_pm MFMA (afrP @ W1pm, held) ----
    f32x4_t accM[2][4];                        // h_pm accumulators (held past B3)
    for (int ntl = 0; ntl < 2; ++ntl)
        for (int mt = 0; mt < 4; ++mt) accM[ntl][mt] = (f32x4_t){0.f, 0.f, 0.f, 0.f};
    #pragma unroll
    for (int ntl = 0; ntl < 2; ++ntl) {
        int nt = w * 2 + ntl;
        bf16x8_t bfr = *(const bf16x8_t*)(w1F + (nt * 64 + lane) * 8);
        #pragma unroll
        for (int mt = 0; mt < 4; ++mt)
            accM[ntl][mt] = __builtin_amdgcn_mfma_f32_16x16x32_bf16(afrP[mt], bfr, accM[ntl][mt], 0, 0, 0);
    }
    f32x4_t acc[2][4];
    {
        float b0 = pb_b2[(w * 2    ) * 16 + ln15];
        float b1 = pb_b2[(w * 2 + 1) * 16 + ln15];
        for (int mt = 0; mt < 4; ++mt) {
            acc[0][mt] = (f32x4_t){b0, b0, b0, b0};
            acc[1][mt] = (f32x4_t){b1, b1, b1, b1};
        }
    }
    #pragma unroll
    for (int kk = 0; kk < 8; ++kk) {
        bf16x8_t afr[4];
        #pragma unroll
        for (int mt = 0; mt < 4; ++mt)
            afr[mt] = *(const bf16x8_t*)&bufR[mt * 16 + ln15][kk * 32 + quad * 8];
        #pragma unroll
        for (int ntl = 0; ntl < 2; ++ntl) {
            int nt = w * 2 + ntl;
            bf16x8_t bfr = *(const bf16x8_t*)(pbw2F + ((nt * 8 + kk) * 64 + lane) * 8);
            #pragma unroll
            for (int mt = 0; mt < 4; ++mt)
                acc[ntl][mt] = __builtin_amdgcn_mfma_f32_16x16x32_bf16(afr[mt], bfr, acc[ntl][mt], 0, 0, 0);
        }
    }
    // peb epilogue -> bufP (free buffer, no barrier needed before write)
    #pragma unroll
    for (int ntl = 0; ntl < 2; ++ntl) {
        int c = (w * 2 + ntl) * 16 + ln15;
        for (int mt = 0; mt < 4; ++mt)
            for (int r = 0; r < 4; r += 2) {
                unsigned int pk = f2bpk(acc[ntl][mt][r], acc[ntl][mt][r + 1]);
                bufP[mt * 16 + quad * 4 + r][c]     = (unsigned short)pk;
                bufP[mt * 16 + quad * 4 + r + 1][c] = (unsigned short)(pk >> 16);
            }
    }
    __syncthreads();                           // B3 (bufR h_pb reads done)

    // ---- h_pm epilogue (relu+pack) -> bufR ----
    #pragma unroll
    for (int ntl = 0; ntl < 2; ++ntl) {
        int c = (w * 2 + ntl) * 16 + ln15;
        for (int mt = 0; mt < 4; ++mt)
            for (int r = 0; r < 4; r += 2) {
                unsigned int pk = f2bpk(fmaxf(accM[ntl][mt][r], 0.f),
                                        fmaxf(accM[ntl][mt][r + 1], 0.f));
                bufR[mt * 16 + quad * 4 + r][c]     = (unsigned short)pk;
                bufR[mt * 16 + quad * 4 + r + 1][c] = (unsigned short)(pk >> 16);
            }
    }
    __syncthreads();                           // B4 (h_pm visible)

    // ---- pem MFMA (bufR @ w2pm) + q prefetch for relation ----
    uint4 qpre[4];
    #pragma unroll
    for (int kk = 0; kk < 4; ++kk)
        qpre[kk] = *(const uint4*)(qm + Pg * 256 + (sub * 4 + kk) * 32 + quad * 8);
    {
        float b0 = pm_b2[(w * 2    ) * 16 + ln15];
        float b1 = pm_b2[(w * 2 + 1) * 16 + ln15];
        for (int mt = 0; mt < 4; ++mt) {
            acc[0][mt] = (f32x4_t){b0, b0, b0, b0};
            acc[1][mt] = (f32x4_t){b1, b1, b1, b1};
        }
    }
    #pragma unroll
    for (int kk = 0; kk < 8; ++kk) {
        bf16x8_t afr[4];
        #pragma unroll
        for (int mt = 0; mt < 4; ++mt)
            afr[mt] = *(const bf16x8_t*)&bufR[mt * 16 + ln15][kk * 32 + quad * 8];
        #pragma unroll
        for (int ntl = 0; ntl < 2; ++ntl) {
            int nt = w * 2 + ntl;
            bf16x8_t bfr = *(const bf16x8_t*)(pmw2F + ((nt * 8 + kk) * 64 + lane) * 8);
            #pragma unroll
            for (int mt = 0; mt < 4; ++mt)
                acc[ntl][mt] = __builtin_amdgcn_mfma_f32_16x16x32_bf16(afr[mt], bfr, acc[ntl][mt], 0, 0, 0);
        }
    }
    __syncthreads();                           // B5 (bufR h_pm reads done)

    // pem epilogue -> bufR
    #pragma unroll
    for (int ntl = 0; ntl < 2; ++ntl) {
        int c = (w * 2 + ntl) * 16 + ln15;
        for (int mt = 0; mt < 4; ++mt)
            for (int r = 0; r < 4; r += 2) {
                unsigned int pk = f2bpk(acc[ntl][mt][r], acc[ntl][mt][r + 1]);
                bufR[mt * 16 + quad * 4 + r][c]     = (unsigned short)pk;
                bufR[mt * 16 + quad * 4 + r + 1][c] = (unsigned short)(pk >> 16);
            }
    }
    __syncthreads();                           // B6 (pem/peb visible)

    // ---- relation + partial logits (K-half = sub), in registers ----
    {
        const bf16x8_t bz = {0, 0, 0, 0, 0, 0, 0, 0};
        f32x4_t lacc = {0.f, 0.f, 0.f, 0.f};
        #pragma unroll
        for (int kk = 0; kk < 4; ++kk) {
            int cb8 = (sub * 4 + kk) * 32 + quad * 8;
            uint4 pm4 = *(const uint4*)&bufR[R0 + ln15][cb8];
            uint4 pb4 = *(const uint4*)&bufP[R0 + ln15][cb8];
            uint4 q4  = qpre[kk];
            union { uint4 u; bf16x8_t v; } rr;
            rr.u.x = relpair(kpre[kk].x, q4.x, pm4.x, pb4.x);
            rr.u.y = relpair(kpre[kk].y, q4.y, pm4.y, pb4.y);
            rr.u.z = relpair(kpre[kk].z, q4.z, pm4.z, pb4.z);
            rr.u.w = relpair(kpre[kk].w, q4.w, pm4.w, pb4.w);
            bf16x8_t bfr = bz;
            if (ln15 < 8) bfr = *(const bf16x8_t*)(we1TF + ln15 * 256 + cb8);
            lacc = __builtin_amdgcn_mfma_f32_16x16x32_bf16(rr.v, bfr, lacc, 0, 0, 0);
        }
        if (ln15 < 8) {
            #pragma unroll
            for (int r = 0; r < 4; ++r)
                usP[sub][R0 + quad * 4 + r][ln15] = lacc[r];
        }
    }
    __syncthreads();                           // B7 (partials visible)

    // ---- combine + BN/relu + logits2 (even wave, lanes<16 = s) ----
    if (sub == 0 && lane < 16) {
        int s = lane;
        float uv[8], l[8];
        #pragma unroll
        for (int g = 0; g < 8; ++g) {
            float x = usP[0][R0 + s][g] + usP[1][R0 + s][g];
            uv[g] = fmaxf(x * swe8[g] + dwe8[g], 0.f);
        }
        #pragma unroll
        for (int g = 0; g < 8; ++g) {
            float x = web2[g];
            for (int gp = 0; gp < 8; ++gp) x += uv[gp] * we2s[gp][g];
            l[g] = x;
        }
        #pragma unroll
        for (int g = 0; g < 8; ++g) us_[R0 + s][g] = l[g];
    }
    WSYNC();

    // ---- softmax over s (even wave, lanes<8 = g) ----
    if (sub == 0 && lane < 8) {
        int g = lane;
        float mx = -1e30f;
        for (int s = 0; s < 16; ++s) mx = fmaxf(mx, us_[R0 + s][g]);
        float e[16], sum = 0.f;
        for (int s = 0; s < 16; ++s) { e[s] = __expf(us_[R0 + s][g] - mx); sum += e[s]; }
        float inv = 1.f / sum;
        for (int s = 0; s < 16; ++s) us_[R0 + s][g] = e[s] * inv;
    }
    __syncthreads();                           // B8 (softmax visible)

    // ---- output: wave pair = 128 lanes, 2 cols each ----
    {
        int idx2 = sub * 64 + lane;
        int c5 = idx2 * 2, g = c5 >> 5;
        float a0 = 0.f, a1 = 0.f;
        #pragma unroll
        for (int s = 0; s < 16; ++s) {
            int rv = rowg_[R0 + s];
            float wv_ = us_[R0 + s][g];
            unsigned int v2 = *(const unsigned int*)(vm + rv * 256 + c5);
            unsigned int p2 = *(const unsigned int*)&bufP[R0 + s][c5];
            a0 += wv_ * (blo(v2) + blo(p2));
            a1 += wv_ * (bhi(v2) + bhi(p2));
        }
        *(float2*)(out + (size_t)Pg * 256 + c5) = make_float2(a0, a1);
    }
}

// ---------------------------------------------------------------------------
extern "C" void kernel_launch(void* const* d_in, const int* in_sizes, int n_in,
                              void* d_out, int out_size, void* d_ws, size_t ws_size,
                              hipStream_t stream)
{
    const float* feats  = (const float*)d_in[0];
    const float* coords = (const float*)d_in[1];
    const int*   index  = (const int*)d_in[2];
    const float* wq     = (const float*)d_in[3];
    const float* bq     = (const float*)d_in[4];
    const float* bnq    = (const float*)d_in[5];
    const float* wk     = (const float*)d_in[6];
    const float* bk     = (const float*)d_in[7];
    const float* bnk    = (const float*)d_in[8];
    const float* wv     = (const float*)d_in[9];
    const float* bv     = (const float*)d_in[10];
    const float* pm_w1  = (const float*)d_in[11];
    const float* pm_b1  = (const float*)d_in[12];
    const float* pm_bn  = (const float*)d_in[13];
    const float* pm_w2  = (const float*)d_in[14];
    const float* pm_b2  = (const float*)d_in[15];
    const float* pb_w1  = (const float*)d_in[16];
    const float* pb_b1  = (const float*)d_in[17];
    const float* pb_bn  = (const float*)d_in[18];
    const float* pb_w2  = (const float*)d_in[19];
    const float* pb_b2  = (const float*)d_in[20];
    const float* we_w1  = (const float*)d_in[21];
    const float* we_b1  = (const float*)d_in[22];
    const float* we_bn  = (const float*)d_in[23];
    const float* we_w2  = (const float*)d_in[24];
    const float* we_b2  = (const float*)d_in[25];

    unsigned short* qkv   = (unsigned short*)d_ws;
    unsigned short* wsT   = qkv + (size_t)3 * 8192 * 256;
    unsigned short* we1TF = wsT + 5 * 65536;
    unsigned short* w1F   = we1TF + 2048;

    const size_t need = (size_t)13275136;
    if (ws_size < need) {
        hipMemsetAsync(d_out, 0, (size_t)out_size * 4, stream);
        return;
    }

    k_prep<<<162,  256, 0, stream>>>(wq, wk, wv, pm_w2, pb_w2,
                                     pm_w1, pm_b1, pm_bn,
                                     pb_w1, pb_b1, pb_bn,
                                     we_w1, wsT, w1F, we1TF);
    k_qkv <<<768,  256, 0, stream>>>(feats, wsT, bq, bnq, bk, bnk, bv, qkv);
    k_main<<<2048, 512, 0, stream>>>(coords, index,
                                     qkv,
                                     qkv + (size_t)8192 * 256,
                                     qkv + (size_t)2 * 8192 * 256,
                                     wsT + 3 * 65536,
                                     wsT + 4 * 65536,
                                     w1F, we1TF,
                                     pm_b2, pb_b2,
                                     we_b1, we_bn, we_w2, we_b2,
                                     (float*)d_out);
}

// Round 3
// 191.347 us; speedup vs baseline: 1.0678x; 1.0354x over previous
//
#include <hip/hip_runtime.h>
#include <hip/hip_bf16.h>

// GroupedVectorSA (gfx950) — ROUND 15: operand-swapped MFMAs (transposed D)
// so every epilogue writes row-contiguous b64 instead of column-strided b16.
// Kills the epilogue LDS bank conflicts (~10% of cycles) + ~100 wave-instrs.
// Weight fragment buffers are layout-isomorphic so k_prep is unchanged.

typedef __attribute__((ext_vector_type(8))) short bf16x8_t;
typedef __attribute__((ext_vector_type(4))) float f32x4_t;

#define BN_EPS 1e-5f
#define WSYNC() asm volatile("s_waitcnt lgkmcnt(0)" ::: "memory")

__device__ __forceinline__ float blo(unsigned int v) {
    union { unsigned int u; float f; } x; x.u = v << 16; return x.f;
}
__device__ __forceinline__ float bhi(unsigned int v) {
    union { unsigned int u; float f; } x; x.u = v & 0xffff0000u; return x.f;
}
__device__ __forceinline__ unsigned int fbits(float f) {
    union { float f; unsigned int u; } x; x.f = f; return x.u;
}
__device__ __forceinline__ unsigned short f2b(float f) {      // RNE fp32->bf16
    unsigned int u = fbits(f);
    return (unsigned short)((u + 0x7fffu + ((u >> 16) & 1u)) >> 16);
}
__device__ __forceinline__ float b2f(unsigned short h) {      // bf16->fp32 exact
    union { unsigned int u; float f; } x; x.u = ((unsigned int)h) << 16; return x.f;
}
__device__ __forceinline__ unsigned int f2bpk(float a, float b) {  // hw packed cvt
    union { __hip_bfloat162 h; unsigned int u; } x;
    x.h = __float22bfloat162_rn(make_float2(a, b));
    return x.u;
}
__device__ __forceinline__ unsigned int relpair(unsigned int kb, unsigned int qb,
                                                unsigned int pm_, unsigned int pb_) {
    float r0 = (blo(kb) - blo(qb)) * blo(pm_) + blo(pb_);
    float r1 = (bhi(kb) - bhi(qb)) * bhi(pm_) + bhi(pb_);
    return f2bpk(r0, r1);
}

// ---------------------------------------------------------------------------
// K0: blocks 0..159: 5 weights -> bf16 fragment-linear. 160: W1 frags. 161: we1TF.
// ---------------------------------------------------------------------------
__global__ __launch_bounds__(256) void k_prep(
    const float* __restrict__ wq, const float* __restrict__ wk,
    const float* __restrict__ wv, const float* __restrict__ pm2,
    const float* __restrict__ pb2,
    const float* __restrict__ pm_w1, const float* __restrict__ pm_b1,
    const float* __restrict__ pm_bn,
    const float* __restrict__ pb_w1, const float* __restrict__ pb_b1,
    const float* __restrict__ pb_bn,
    const float* __restrict__ we_w1,
    unsigned short* __restrict__ wsT, unsigned short* __restrict__ w1F,
    unsigned short* __restrict__ we1TF)
{
    const int bid = blockIdx.x, t = threadIdx.x;
    if (bid < 160) {
        __shared__ unsigned short T[32][72];
        const int mat = bid >> 5;
        const int kk  = (bid >> 2) & 7;
        const int ntq = bid & 3;
        const float* s = (mat == 0) ? wq : (mat == 1) ? wk : (mat == 2) ? wv
                         : (mat == 3) ? pm2 : pb2;
        {
            int c = t & 63, r0 = t >> 6;
            for (int i = 0; i < 8; ++i) {
                int r = r0 + i * 4;
                T[r][c] = f2b(s[(kk * 32 + r) * 256 + ntq * 64 + c]);
            }
        }
        __syncthreads();
        {
            int seg = t >> 6, lane = t & 63;
            int col = seg * 16 + (lane & 15);
            int kr  = (lane >> 4) * 8;
            unsigned int v[8];
            #pragma unroll
            for (int j = 0; j < 8; ++j) v[j] = T[kr + j][col];
            uint4 o;
            o.x = v[0] | (v[1] << 16);
            o.y = v[2] | (v[3] << 16);
            o.z = v[4] | (v[5] << 16);
            o.w = v[6] | (v[7] << 16);
            *(uint4*)(wsT + mat * 65536 + (ntq * 4 + seg) * 4096 + kk * 512 + lane * 8) = o;
        }
    } else if (bid == 160) {
        // Build W1 B-fragments (K-slot packed, BN folded), pass0=pm, pass1=pb.
        int c = t;                      // column 0..255
        int nt = c >> 4, l15 = c & 15;
        float sm = pm_bn[c] / sqrtf(pm_bn[768 + c] + BN_EPS);
        float sb = pb_bn[c] / sqrtf(pb_bn[768 + c] + BN_EPS);
        float W[2][4];
        W[0][0] = pm_w1[c] * sm; W[0][1] = pm_w1[256 + c] * sm;
        W[0][2] = pm_w1[512 + c] * sm;
        W[0][3] = (pm_b1[c] - pm_bn[512 + c]) * sm + pm_bn[256 + c];
        W[1][0] = pb_w1[c] * sb; W[1][1] = pb_w1[256 + c] * sb;
        W[1][2] = pb_w1[512 + c] * sb;
        W[1][3] = (pb_b1[c] - pb_bn[512 + c]) * sb + pb_bn[256 + c];
        for (int pass = 0; pass < 2; ++pass) {
            unsigned short xh = f2b(W[pass][0]), xl = f2b(W[pass][0] - b2f(xh));
            unsigned short yh = f2b(W[pass][1]), yl = f2b(W[pass][1] - b2f(yh));
            unsigned short zh = f2b(W[pass][2]), zl = f2b(W[pass][2] - b2f(zh));
            unsigned short bh = f2b(W[pass][3]), bl = f2b(W[pass][3] - b2f(bh));
            unsigned short sl[16] = { xh, xh, xl, yh, yh, yl, zh, zh, zl,
                                      bh, bl, 0, 0, 0, 0, 0 };
            for (int q = 0; q < 4; ++q)
                for (int j = 0; j < 8; ++j)
                    w1F[((pass * 16 + nt) * 64 + q * 16 + l15) * 8 + j] =
                        (q < 2) ? sl[q * 8 + j] : (unsigned short)0;
        }
    } else {
        for (int j = 0; j < 8; ++j) {
            int e = t * 8 + j;
            int g = e >> 8, c = e & 255;
            we1TF[g * 256 + c] = f2b(we_w1[c * 8 + g]);
        }
    }
}

// ---------------------------------------------------------------------------
// K1: q/k/v GEMM. grid=768, blk=256. (unchanged)
// ---------------------------------------------------------------------------
__global__ __launch_bounds__(256) void k_qkv(
    const float* __restrict__ feats,
    const unsigned short* __restrict__ wT,
    const float* __restrict__ bq, const float* __restrict__ bnq,
    const float* __restrict__ bk, const float* __restrict__ bnk,
    const float* __restrict__ bv,
    unsigned short* __restrict__ qkv)
{
    __shared__ unsigned short A[32][264];
    const int t    = threadIdx.x;
    const int widx = blockIdx.x >> 8;
    const int mb   = blockIdx.x & 255;

    for (int i = 0; i < 8; ++i) {
        int row = 4 * i + (t >> 6), col = (t & 63) * 4;
        float4 f = *(const float4*)(feats + (mb * 32 + row) * 256 + col);
        *(uint2*)&A[row][col] = make_uint2(f2bpk(f.x, f.y), f2bpk(f.z, f.w));
    }
    __syncthreads();

    const int lane = t & 63, w = t >> 6;
    const int ln15 = lane & 15, quad = lane >> 4;
    const int mt = w & 1, nh = w >> 1;

    bf16x8_t afr[8];
    #pragma unroll
    for (int kk = 0; kk < 8; ++kk)
        afr[kk] = *(const bf16x8_t*)&A[mt * 16 + ln15][kk * 32 + quad * 8];

    const unsigned short* W = wT + widx * 65536;
    const float* bias = (widx == 0) ? bq : (widx == 1) ? bk : bv;
    const float* bn   = (widx == 0) ? bnq : (widx == 1) ? bnk : nullptr;
    unsigned short* dst = qkv + (size_t)widx * 8192 * 256;

    f32x4_t acc[8];
    for (int j = 0; j < 8; ++j) acc[j] = (f32x4_t){0.f, 0.f, 0.f, 0.f};

    #pragma unroll
    for (int kk = 0; kk < 8; ++kk) {
        #pragma unroll
        for (int j = 0; j < 8; ++j) {
            int nt = nh * 8 + j;
            bf16x8_t bfr = *(const bf16x8_t*)(W + ((nt * 8 + kk) * 64 + lane) * 8);
            acc[j] = __builtin_amdgcn_mfma_f32_16x16x32_bf16(afr[kk], bfr, acc[j], 0, 0, 0);
        }
    }

    float bb[8], sc[8], mu[8], be[8];
    #pragma unroll
    for (int j = 0; j < 8; ++j) {
        int c = (nh * 8 + j) * 16 + ln15;
        bb[j] = bias[c];
        if (bn) {
            sc[j] = bn[c] / sqrtf(bn[768 + c] + BN_EPS);
            be[j] = bn[256 + c];
            mu[j] = bn[512 + c];
        }
    }
    __syncthreads();
    #pragma unroll
    for (int j = 0; j < 8; ++j) {
        int c = (nh * 8 + j) * 16 + ln15;
        float y[4];
        for (int r = 0; r < 4; ++r) {
            y[r] = acc[j][r] + bb[j];
            if (bn) y[r] = fmaxf((y[r] - mu[j]) * sc[j] + be[j], 0.f);
        }
        for (int r = 0; r < 4; r += 2) {
            unsigned int pk = f2bpk(y[r], y[r + 1]);
            A[mt * 16 + quad * 4 + r][c]     = (unsigned short)pk;
            A[mt * 16 + quad * 4 + r + 1][c] = (unsigned short)(pk >> 16);
        }
    }
    __syncthreads();
    {
        int row = t >> 3, cc = (t & 7) * 32;
        #pragma unroll
        for (int j = 0; j < 4; ++j) {
            uint4 v = *(const uint4*)&A[row][cc + 8 * j];
            *(uint4*)(dst + (mb * 32 + row) * 256 + cc + 8 * j) = v;
        }
    }
}

// ---------------------------------------------------------------------------
// K2: fused main. 512 threads (8 waves), 4 points/block, wave pair per point.
// grid=2048. LDS ~78.4KB -> 2 blocks/CU. All tile MFMAs operand-swapped:
// D comes out transposed -> epilogues are row-contiguous b64 writes.
// ---------------------------------------------------------------------------
__global__ __launch_bounds__(512, 4) void k_main(
    const float* __restrict__ coords,
    const int*   __restrict__ index,
    const unsigned short* __restrict__ qm,
    const unsigned short* __restrict__ km,
    const unsigned short* __restrict__ vm,
    const unsigned short* __restrict__ pmw2F,
    const unsigned short* __restrict__ pbw2F,
    const unsigned short* __restrict__ w1F,
    const unsigned short* __restrict__ we1TF,
    const float* __restrict__ pm_b2, const float* __restrict__ pb_b2,
    const float* __restrict__ we_b1, const float* __restrict__ we_bn,
    const float* __restrict__ we_w2, const float* __restrict__ we_b2,
    float* __restrict__ out)
{
    __shared__ unsigned short bufR[64][264];   // h_pb -> h_pm -> pem
    __shared__ unsigned short bufP[64][264];   // peb
    __shared__ unsigned short posX[64][32];    // B-operand K-slots (hi/lo packed)
    __shared__ float usP[2][64][8];            // partial logits (K-split halves)
    __shared__ float us_[64][8];               // logits -> softmax w
    __shared__ int   rowg_[64];
    __shared__ float we2s[8][8];
    __shared__ float web2[8], swe8[8], dwe8[8];

    const int t   = threadIdx.x;
    const int P0  = blockIdx.x * 4;
    const int bb_ = P0 >> 12;
    const int w = t >> 6, lane = t & 63;
    const int ln15 = lane & 15, quad = lane >> 4;
    const int p   = w >> 1, sub = w & 1;       // wave pair (2p, 2p+1) owns point p
    const int R0  = p * 16;
    const int Pg  = P0 + p;

    // ---- per-lane neighbor row (s=ln15) + k prefetch, K-half sub ----
    const int rg = (bb_ << 12) + index[Pg * 16 + ln15];
    uint4 kpre[4];
    #pragma unroll
    for (int kk = 0; kk < 4; ++kk)
        kpre[kk] = *(const uint4*)(km + rg * 256 + (sub * 4 + kk) * 32 + quad * 8);

    // ---- stage posX K-slots (t<64 -> row m=t) + small consts ----
    if (t < 64) {
        int m  = t;
        int Pr = P0 + (m >> 4);
        int rs = (bb_ << 12) + index[Pr * 16 + (m & 15)];
        rowg_[m] = rs;
        float x = coords[Pr * 3 + 0] - coords[rs * 3 + 0];
        float y = coords[Pr * 3 + 1] - coords[rs * 3 + 1];
        float z = coords[Pr * 3 + 2] - coords[rs * 3 + 2];
        unsigned short xh = f2b(x), xl = f2b(x - b2f(xh));
        unsigned short yh = f2b(y), yl = f2b(y - b2f(yh));
        unsigned short zh = f2b(z), zl = f2b(z - b2f(zh));
        const unsigned short one = 0x3f80;
        posX[m][0] = xh; posX[m][1] = xl; posX[m][2] = xh;
        posX[m][3] = yh; posX[m][4] = yl; posX[m][5] = yh;
        posX[m][6] = zh; posX[m][7] = zl; posX[m][8] = zh;
        posX[m][9] = one; posX[m][10] = one;
        #pragma unroll
        for (int j2 = 11; j2 < 32; ++j2) posX[m][j2] = 0;
        we2s[m >> 3][m & 7] = we_w2[m];
    }
    if (t < 8) {
        float s = we_bn[t] / sqrtf(we_bn[24 + t] + BN_EPS);
        swe8[t] = s;
        dwe8[t] = (we_b1[t] - we_bn[16 + t]) * s + we_bn[8 + t];
        web2[t] = we_b2[t];
    }
    __syncthreads();                           // B1 (posX visible)

    // ---- pos fragments (B-operand of swapped h-MFMAs, held in regs) ----
    bf16x8_t afrP[4];
    #pragma unroll
    for (int mt = 0; mt < 4; ++mt)
        afrP[mt] = *(const bf16x8_t*)&posX[mt * 16 + ln15][quad * 8];

    // ---- h_pb = relu(pos @ W1pb) via swapped MFMA -> bufR (b64 writes) ----
    {
        f32x4_t hb[2][4];
        for (int ntl = 0; ntl < 2; ++ntl)
            for (int mt = 0; mt < 4; ++mt) hb[ntl][mt] = (f32x4_t){0.f, 0.f, 0.f, 0.f};
        #pragma unroll
        for (int ntl = 0; ntl < 2; ++ntl) {
            int nt = w * 2 + ntl;
            bf16x8_t wfr = *(const bf16x8_t*)(w1F + ((16 + nt) * 64 + lane) * 8);
            #pragma unroll
            for (int mt = 0; mt < 4; ++mt)
                hb[ntl][mt] = __builtin_amdgcn_mfma_f32_16x16x32_bf16(wfr, afrP[mt], hb[ntl][mt], 0, 0, 0);
        }
        #pragma unroll
        for (int ntl = 0; ntl < 2; ++ntl) {
            int cb = w * 32 + ntl * 16 + quad * 4;
            #pragma unroll
            for (int mt = 0; mt < 4; ++mt) {
                unsigned int pk0 = f2bpk(fmaxf(hb[ntl][mt][0], 0.f), fmaxf(hb[ntl][mt][1], 0.f));
                unsigned int pk1 = f2bpk(fmaxf(hb[ntl][mt][2], 0.f), fmaxf(hb[ntl][mt][3], 0.f));
                *(uint2*)&bufR[mt * 16 + ln15][cb] = make_uint2(pk0, pk1);
            }
        }
    }
    __syncthreads();                           // B2 (h_pb visible)

    // ---- phase: peb MFMA (w2pb^T x h) + h_pm MFMA (W1pm^T x pos, held) ----
    f32x4_t accM[2][4];                        // h_pm accumulators (held past B3)
    for (int ntl = 0; ntl < 2; ++ntl)
        for (int mt = 0; mt < 4; ++mt) accM[ntl][mt] = (f32x4_t){0.f, 0.f, 0.f, 0.f};
    #pragma unroll
    for (int ntl = 0; ntl < 2; ++ntl) {
        int nt = w * 2 + ntl;
        bf16x8_t wfr = *(const bf16x8_t*)(w1F + (nt * 64 + lane) * 8);
        #pragma unroll
        for (int mt = 0; mt < 4; ++mt)
            accM[ntl][mt] = __builtin_amdgcn_mfma_f32_16x16x32_bf16(wfr, afrP[mt], accM[ntl][mt], 0, 0, 0);
    }
    f32x4_t acc[2][4];
    {
        f32x4_t b0 = *(const f32x4_t*)(pb_b2 + (w * 2    ) * 16 + quad * 4);
        f32x4_t b1 = *(const f32x4_t*)(pb_b2 + (w * 2 + 1) * 16 + quad * 4);
        for (int mt = 0; mt < 4; ++mt) { acc[0][mt] = b0; acc[1][mt] = b1; }
    }
    #pragma unroll
    for (int kk = 0; kk < 8; ++kk) {
        bf16x8_t afr[4];
        #pragma unroll
        for (int mt = 0; mt < 4; ++mt)
            afr[mt] = *(const bf16x8_t*)&bufR[mt * 16 + ln15][kk * 32 + quad * 8];
        #pragma unroll
        for (int ntl = 0; ntl < 2; ++ntl) {
            int nt = w * 2 + ntl;
            bf16x8_t wfr = *(const bf16x8_t*)(pbw2F + ((nt * 8 + kk) * 64 + lane) * 8);
            #pragma unroll
            for (int mt = 0; mt < 4; ++mt)
                acc[ntl][mt] = __builtin_amdgcn_mfma_f32_16x16x32_bf16(wfr, afr[mt], acc[ntl][mt], 0, 0, 0);
        }
    }
    // peb epilogue -> bufP (free buffer, no barrier needed before write)
    #pragma unroll
    for (int ntl = 0; ntl < 2; ++ntl) {
        int cb = w * 32 + ntl * 16 + quad * 4;
        #pragma unroll
        for (int mt = 0; mt < 4; ++mt) {
            unsigned int pk0 = f2bpk(acc[ntl][mt][0], acc[ntl][mt][1]);
            unsigned int pk1 = f2bpk(acc[ntl][mt][2], acc[ntl][mt][3]);
            *(uint2*)&bufP[mt * 16 + ln15][cb] = make_uint2(pk0, pk1);
        }
    }
    __syncthreads();                           // B3 (bufR h_pb reads done)

    // ---- h_pm epilogue (relu+pack) -> bufR ----
    #pragma unroll
    for (int ntl = 0; ntl < 2; ++ntl) {
        int cb = w * 32 + ntl * 16 + quad * 4;
        #pragma unroll
        for (int mt = 0; mt < 4; ++mt) {
            unsigned int pk0 = f2bpk(fmaxf(accM[ntl][mt][0], 0.f), fmaxf(accM[ntl][mt][1], 0.f));
            unsigned int pk1 = f2bpk(fmaxf(accM[ntl][mt][2], 0.f), fmaxf(accM[ntl][mt][3], 0.f));
            *(uint2*)&bufR[mt * 16 + ln15][cb] = make_uint2(pk0, pk1);
        }
    }
    __syncthreads();                           // B4 (h_pm visible)

    // ---- pem MFMA (w2pm^T x h) + q prefetch for relation ----
    uint4 qpre[4];
    #pragma unroll
    for (int kk = 0; kk < 4; ++kk)
        qpre[kk] = *(const uint4*)(qm + Pg * 256 + (sub * 4 + kk) * 32 + quad * 8);
    {
        f32x4_t b0 = *(const f32x4_t*)(pm_b2 + (w * 2    ) * 16 + quad * 4);
        f32x4_t b1 = *(const f32x4_t*)(pm_b2 + (w * 2 + 1) * 16 + quad * 4);
        for (int mt = 0; mt < 4; ++mt) { acc[0][mt] = b0; acc[1][mt] = b1; }
    }
    #pragma unroll
    for (int kk = 0; kk < 8; ++kk) {
        bf16x8_t afr[4];
        #pragma unroll
        for (int mt = 0; mt < 4; ++mt)
            afr[mt] = *(const bf16x8_t*)&bufR[mt * 16 + ln15][kk * 32 + quad * 8];
        #pragma unroll
        for (int ntl = 0; ntl < 2; ++ntl) {
            int nt = w * 2 + ntl;
            bf16x8_t wfr = *(const bf16x8_t*)(pmw2F + ((nt * 8 + kk) * 64 + lane) * 8);
            #pragma unroll
            for (int mt = 0; mt < 4; ++mt)
                acc[ntl][mt] = __builtin_amdgcn_mfma_f32_16x16x32_bf16(wfr, afr[mt], acc[ntl][mt], 0, 0, 0);
        }
    }
    __syncthreads();                           // B5 (bufR h_pm reads done)

    // pem epilogue -> bufR
    #pragma unroll
    for (int ntl = 0; ntl < 2; ++ntl) {
        int cb = w * 32 + ntl * 16 + quad * 4;
        #pragma unroll
        for (int mt = 0; mt < 4; ++mt) {
            unsigned int pk0 = f2bpk(acc[ntl][mt][0], acc[ntl][mt][1]);
            unsigned int pk1 = f2bpk(acc[ntl][mt][2], acc[ntl][mt][3]);
            *(uint2*)&bufR[mt * 16 + ln15][cb] = make_uint2(pk0, pk1);
        }
    }
    __syncthreads();                           // B6 (pem/peb visible)

    // ---- relation + partial logits (K-half = sub), swapped MFMA ----
    {
        const bf16x8_t bz = {0, 0, 0, 0, 0, 0, 0, 0};
        f32x4_t lacc = {0.f, 0.f, 0.f, 0.f};
        #pragma unroll
        for (int kk = 0; kk < 4; ++kk) {
            int cb8 = (sub * 4 + kk) * 32 + quad * 8;
            uint4 pm4 = *(const uint4*)&bufR[R0 + ln15][cb8];
            uint4 pb4 = *(const uint4*)&bufP[R0 + ln15][cb8];
            uint4 q4  = qpre[kk];
            union { uint4 u; bf16x8_t v; } rr;
            rr.u.x = relpair(kpre[kk].x, q4.x, pm4.x, pb4.x);
            rr.u.y = relpair(kpre[kk].y, q4.y, pm4.y, pb4.y);
            rr.u.z = relpair(kpre[kk].z, q4.z, pm4.z, pb4.z);
            rr.u.w = relpair(kpre[kk].w, q4.w, pm4.w, pb4.w);
            bf16x8_t wfr = bz;
            if (ln15 < 8) wfr = *(const bf16x8_t*)(we1TF + ln15 * 256 + cb8);
            lacc = __builtin_amdgcn_mfma_f32_16x16x32_bf16(wfr, rr.v, lacc, 0, 0, 0);
        }
        // D[g = quad*4+r][s = ln15]: rows g<8 valid -> quad<2 stores float4
        if (quad < 2)
            *(f32x4_t*)&usP[sub][R0 + ln15][quad * 4] = lacc;
    }
    __syncthreads();                           // B7 (partials visible)

    // ---- combine + BN/relu + logits2 (even wave, lanes<16 = s) ----
    if (sub == 0 && lane < 16) {
        int s = lane;
        float uv[8], l[8];
        #pragma unroll
        for (int g = 0; g < 8; ++g) {
            float x = usP[0][R0 + s][g] + usP[1][R0 + s][g];
            uv[g] = fmaxf(x * swe8[g] + dwe8[g], 0.f);
        }
        #pragma unroll
        for (int g = 0; g < 8; ++g) {
            float x = web2[g];
            for (int gp = 0; gp < 8; ++gp) x += uv[gp] * we2s[gp][g];
            l[g] = x;
        }
        #pragma unroll
        for (int g = 0; g < 8; ++g) us_[R0 + s][g] = l[g];
    }
    WSYNC();

    // ---- softmax over s (even wave, lanes<8 = g) ----
    if (sub == 0 && lane < 8) {
        int g = lane;
        float mx = -1e30f;
        for (int s = 0; s < 16; ++s) mx = fmaxf(mx, us_[R0 + s][g]);
        float e[16], sum = 0.f;
        for (int s = 0; s < 16; ++s) { e[s] = __expf(us_[R0 + s][g] - mx); sum += e[s]; }
        float inv = 1.f / sum;
        for (int s = 0; s < 16; ++s) us_[R0 + s][g] = e[s] * inv;
    }
    __syncthreads();                           // B8 (softmax visible)

    // ---- output: wave pair = 128 lanes, 2 cols each ----
    {
        int idx2 = sub * 64 + lane;
        int c5 = idx2 * 2, g = c5 >> 5;
        float a0 = 0.f, a1 = 0.f;
        #pragma unroll
        for (int s = 0; s < 16; ++s) {
            int rv = rowg_[R0 + s];
            float wv_ = us_[R0 + s][g];
            unsigned int v2 = *(const unsigned int*)(vm + rv * 256 + c5);
            unsigned int p2 = *(const unsigned int*)&bufP[R0 + s][c5];
            a0 += wv_ * (blo(v2) + blo(p2));
            a1 += wv_ * (bhi(v2) + bhi(p2));
        }
        *(float2*)(out + (size_t)Pg * 256 + c5) = make_float2(a0, a1);
    }
}

// ---------------------------------------------------------------------------
extern "C" void kernel_launch(void* const* d_in, const int* in_sizes, int n_in,
                              void* d_out, int out_size, void* d_ws, size_t ws_size,
                              hipStream_t stream)
{
    const float* feats  = (const float*)d_in[0];
    const float* coords = (const float*)d_in[1];
    const int*   index  = (const int*)d_in[2];
    const float* wq     = (const float*)d_in[3];
    const float* bq     = (const float*)d_in[4];
    const float* bnq    = (const float*)d_in[5];
    const float* wk     = (const float*)d_in[6];
    const float* bk     = (const float*)d_in[7];
    const float* bnk    = (const float*)d_in[8];
    const float* wv     = (const float*)d_in[9];
    const float* bv     = (const float*)d_in[10];
    const float* pm_w1  = (const float*)d_in[11];
    const float* pm_b1  = (const float*)d_in[12];
    const float* pm_bn  = (const float*)d_in[13];
    const float* pm_w2  = (const float*)d_in[14];
    const float* pm_b2  = (const float*)d_in[15];
    const float* pb_w1  = (const float*)d_in[16];
    const float* pb_b1  = (const float*)d_in[17];
    const float* pb_bn  = (const float*)d_in[18];
    const float* pb_w2  = (const float*)d_in[19];
    const float* pb_b2  = (const float*)d_in[20];
    const float* we_w1  = (const float*)d_in[21];
    const float* we_b1  = (const float*)d_in[22];
    const float* we_bn  = (const float*)d_in[23];
    const float* we_w2  = (const float*)d_in[24];
    const float* we_b2  = (const float*)d_in[25];

    unsigned short* qkv   = (unsigned short*)d_ws;
    unsigned short* wsT   = qkv + (size_t)3 * 8192 * 256;
    unsigned short* we1TF = wsT + 5 * 65536;
    unsigned short* w1F   = we1TF + 2048;

    const size_t need = (size_t)13275136;
    if (ws_size < need) {
        hipMemsetAsync(d_out, 0, (size_t)out_size * 4, stream);
        return;
    }

    k_prep<<<162,  256, 0, stream>>>(wq, wk, wv, pm_w2, pb_w2,
                                     pm_w1, pm_b1, pm_bn,
                                     pb_w1, pb_b1, pb_bn,
                                     we_w1, wsT, w1F, we1TF);
    k_qkv <<<768,  256, 0, stream>>>(feats, wsT, bq, bnq, bk, bnk, bv, qkv);
    k_main<<<2048, 512, 0, stream>>>(coords, index,
                                     qkv,
                                     qkv + (size_t)8192 * 256,
                                     qkv + (size_t)2 * 8192 * 256,
                                     wsT + 3 * 65536,
                                     wsT + 4 * 65536,
                                     w1F, we1TF,
                                     pm_b2, pb_b2,
                                     we_b1, we_bn, we_w2, we_b2,
                                     (float*)d_out);
}